// Round 14
// baseline (78.235 us; speedup 1.0000x reference)
//
#include <hip/hip_runtime.h>

// TaskAlignedAssigner (YOLO TAL) for bs=32, A=8400, M=32, C=80, K=13.
// Outputs (concat, float32): labels [b,A], boxes [b,A,4], scores [b,A,80], fg [b,A].
// 2-kernel design:
//   kAB : 256 blocks (1/CU, guaranteed co-resident). Each block: one WAVE per
//         gt -> 13 candidate slots (proven kA_topk body) -> publish MAGIC flag.
//         Block 8b+7 additionally resolves batch b once its 8 flags are set:
//         lite resolver (416-slot dup-scan, ~9KB LDS) -> dense d_meta[b,a].
//         Poison-proof: producers STORE MAGIC (any prior state ok); resolver
//         resets flags to 0 before kernel end.
//   kC  : fillBuffer-shaped streaming writer (nontemporal stores).

#define BS 32
#define A_N 8400
#define M_N 32
#define C_N 80
#define TOPK 13
#define EPSF 1e-9f
#define NSLOT (M_N * TOPK)     // 416 slots per batch
#define NBA (BS * A_N)         // 268800
#define SCORE_BLKS 4200        // 5,376,000 f4 / 1280 per block
#define REST_BLKS 263          // ceil(268800 / 1024)
#define MAGIC 0x5A17C0DEDEADBEEFull

typedef float vf4 __attribute__((ext_vector_type(4)));

__device__ __forceinline__ void nt_store_f4(float4 v, float4* p) {
    __builtin_nontemporal_store(*(vf4*)&v, (vf4*)p);
}

__device__ __forceinline__ float iou_f(float4 g, float4 p, float agt, float apd) {
    float lx = fmaxf(g.x, p.x), ly = fmaxf(g.y, p.y);
    float rx = fminf(g.z, p.z), ry = fminf(g.w, p.w);
    float w = fmaxf(rx - lx, 0.f), h = fmaxf(ry - ly, 0.f);
    float inter = w * h;
    return inter / (agt + apd - inter + EPSF);
}

__device__ __forceinline__ unsigned long long umax64(unsigned long long a, unsigned long long b) {
    return a > b ? a : b;
}

__global__ __launch_bounds__(256) void kAB(
    const float* __restrict__ pd, const float* __restrict__ score,
    const int* __restrict__ labels, const float* __restrict__ gt,
    const float* __restrict__ maskgt,
    unsigned long long* __restrict__ done,
    int* __restrict__ cand_idx, float* __restrict__ cand_met,
    float* __restrict__ cand_ov, uint2* __restrict__ d_meta)
{
    // Lite resolver LDS (~9.3 KB uniform; no occupancy impact on producers).
    __shared__ int   s_sa[NSLOT];
    __shared__ float s_sm[NSLOT], s_so[NSLOT];
    __shared__ int   s_rm[NSLOT];            // -2 single, >=0 multi owner m, -1 none
    __shared__ float s_ral[NSLOT];
    __shared__ float4 s_gt[M_N];
    __shared__ int s_lb[M_N];
    __shared__ float s_pal[M_N], s_pov[M_N];

    const int t = threadIdx.x;
    const int wave = t >> 6;
    const int lane = t & 63;
    const int bm = blockIdx.x * 4 + wave;
    const int bp = bm >> 5;

    // ---------------- producer: proven kA_topk body ----------------
    if (maskgt[bm] <= 0.f) {                 // masked gt -> no candidates
        if (lane < TOPK) cand_idx[bm * TOPK + lane] = -1;
    } else {
        const float4 g = ((const float4*)gt)[bm];
        const float agt = (g.z - g.x) * (g.w - g.y);
        const float4* pdb = (const float4*)pd + (size_t)bp * A_N;
        const int lbl = labels[bm];
        const float* scb = score + (size_t)bp * A_N * C_N + lbl;

        int il0, nx0, jl0, ny0, il1, nx1, jl1, ny1, il2, nx2, jl2, ny2;
        int c0, c1, c2;
        {
#define RANGE(sv, nv, lo_out, cnt_out, e_lo, e_hi)                         \
        {                                                                  \
            int lo = (int)floorf(e_lo / sv - 0.5f) - 1; lo = max(lo, 0);   \
            while (lo < nv && !(((float)lo + 0.5f) * sv > e_lo)) ++lo;     \
            int hi = (int)ceilf(e_hi / sv - 0.5f) + 1; hi = min(hi, nv-1); \
            while (hi >= 0 && !(((float)hi + 0.5f) * sv < e_hi)) --hi;     \
            lo_out = lo; cnt_out = max(hi - lo + 1, 0);                    \
        }
            RANGE(8.f, 80, il0, nx0, g.x, g.z) RANGE(8.f, 80, jl0, ny0, g.y, g.w)
            RANGE(16.f, 40, il1, nx1, g.x, g.z) RANGE(16.f, 40, jl1, ny1, g.y, g.w)
            RANGE(32.f, 20, il2, nx2, g.x, g.z) RANGE(32.f, 20, jl2, ny2, g.y, g.w)
#undef RANGE
            c0 = nx0 * ny0; c1 = nx1 * ny1; c2 = nx2 * ny2;
        }
        const int T = c0 + c1 + c2;          // <= 305 for wh<=120

        unsigned long long keys[6];
        #pragma unroll
        for (int r = 0; r < 6; ++r) {
            keys[r] = 0ull;
            const int idx = r * 64 + lane;
            if (idx < T) {
                int q, n, gbase, il, jl, nx;
                if (idx < c0)           { q = idx;           n = 80; gbase = 0;    il = il0; jl = jl0; nx = nx0; }
                else if (idx < c0 + c1) { q = idx - c0;      n = 40; gbase = 6400; il = il1; jl = jl1; nx = nx1; }
                else                    { q = idx - c0 - c1; n = 20; gbase = 8000; il = il2; jl = jl2; nx = nx2; }
                const int row = q / nx, col = q - row * nx;
                const int a = gbase + (jl + row) * n + (il + col);
                float4 p = pdb[a];
                float apd = (p.z - p.x) * (p.w - p.y);
                float iou = iou_f(g, p, agt, apd);
                float sv = scb[(size_t)a * C_N];
                float i2 = iou * iou;
                float met = sv * i2 * i2 * i2;
                if (met > 0.f)
                    keys[r] = ((unsigned long long)__float_as_uint(met) << 32)
                            | (unsigned)(~(unsigned)a);
            }
        }

        unsigned long long pick = 0ull;
        for (int k = 0; k < TOPK; ++k) {
            unsigned long long mx = 0ull;
            #pragma unroll
            for (int r = 0; r < 6; ++r) mx = umax64(mx, keys[r]);
            #pragma unroll
            for (int s = 32; s > 0; s >>= 1)
                mx = umax64(mx, (unsigned long long)__shfl_xor((long long)mx, s));
            if (mx == 0ull) break;           // uniform across wave
            if (lane == k) pick = mx;
            #pragma unroll
            for (int r = 0; r < 6; ++r) if (keys[r] == mx) keys[r] = 0ull;
        }

        if (lane < TOPK && pick) {
            const int a = (int)(~(unsigned)(pick & 0xFFFFFFFFu));
            const float v = __uint_as_float((unsigned)(pick >> 32));
            float4 p = pdb[a];
            float apd = (p.z - p.x) * (p.w - p.y);
            const int slot = bm * TOPK + lane;
            cand_idx[slot] = a; cand_met[slot] = v; cand_ov[slot] = iou_f(g, p, agt, apd);
        }

        const int npos = __popcll(__ballot(pick != 0ull));
        const int nfill = TOPK - npos;
        if (nfill > 0) {
            bool ing = false; float iou = 0.f, met = 0.f;
            if (lane < 32) {
                const float cx = ((float)lane + 0.5f) * 8.f, cy = 4.0f;
                ing = (cx > g.x) && (cy > g.y) && (cx < g.z) && (cy < g.w);
                if (ing) {
                    float4 p = pdb[lane];
                    float apd = (p.z - p.x) * (p.w - p.y);
                    iou = iou_f(g, p, agt, apd);
                    float i2 = iou * iou;
                    met = scb[(size_t)lane * C_N] * i2 * i2 * i2;
                }
            }
            const bool z = (lane < 32) && !(met > 0.f);
            const unsigned zm32 = (unsigned)__ballot(z);
            const int ingi = ing ? 1 : 0;

            int q = lane - npos; if (q < 0) q = 0;
            unsigned mm = zm32;
            for (int i = 0; i < q; ++i) mm &= mm - 1;
            const int aq = mm ? __builtin_ctz(mm) : 0;
            const int f_ing = __shfl(ingi, aq);
            const float f_iou = __shfl(iou, aq);

            if (lane >= npos && lane < TOPK) {
                const int slot = bm * TOPK + lane;
                if (mm != 0u && f_ing) {
                    cand_idx[slot] = aq; cand_met[slot] = 0.f; cand_ov[slot] = f_iou;
                } else {
                    cand_idx[slot] = -1;
                }
            }
        }
    }

    // Publish.
    __threadfence();
    __syncthreads();
    if (t == 0)
        __hip_atomic_store(&done[blockIdx.x], MAGIC,
                           __ATOMIC_RELEASE, __HIP_MEMORY_SCOPE_AGENT);

    if ((blockIdx.x & 7) != 7) return;

    // ---------------- lite resolver for batch b ----------------
    const int b = blockIdx.x >> 3;
    const size_t base = (size_t)b * A_N;

    if (t < M_N) {
        s_gt[t] = ((const float4*)gt)[b * M_N + t];
        s_lb[t] = labels[b * M_N + t];
        s_pal[t] = 0.f; s_pov[t] = 0.f;
    }
    if (t < 8) {
        while (__hip_atomic_load(&done[b * 8 + t], __ATOMIC_ACQUIRE,
                                 __HIP_MEMORY_SCOPE_AGENT) != MAGIC)
            __builtin_amdgcn_s_sleep(2);
    }
    __syncthreads();
    if (t < 8)        // reset so next replay cannot pass the spin early
        __hip_atomic_store(&done[b * 8 + t], 0ull,
                           __ATOMIC_RELAXED, __HIP_MEMORY_SCOPE_AGENT);

    // Coherence-point reads of the batch's slots.
    for (int i = t; i < NSLOT; i += 256) {
        const int gi = b * NSLOT + i;
        s_sa[i] = __hip_atomic_load(&cand_idx[gi], __ATOMIC_RELAXED, __HIP_MEMORY_SCOPE_AGENT);
        s_sm[i] = __hip_atomic_load(&cand_met[gi], __ATOMIC_RELAXED, __HIP_MEMORY_SCOPE_AGENT);
        s_so[i] = __hip_atomic_load(&cand_ov[gi], __ATOMIC_RELAXED, __HIP_MEMORY_SCOPE_AGENT);
    }
    __syncthreads();

    // Dup-scan per slot; singles feed maxima; first multi slot resolves.
    const float4* pdb = (const float4*)pd + base;
    for (int i = t; i < NSLOT; i += 256) {
        const int a = s_sa[i];
        s_rm[i] = -1;
        if (a < 0) continue;
        int cnt = 0, minj = NSLOT;
        for (int j = 0; j < NSLOT; ++j) {
            if (s_sa[j] == a) { ++cnt; if (j < minj) minj = j; }
        }
        if (cnt == 1) {
            const int m = i / TOPK;
            atomicMax((int*)&s_pal[m], __float_as_int(s_sm[i]));
            atomicMax((int*)&s_pov[m], __float_as_int(s_so[i]));
            s_rm[i] = -2;
        } else if (minj == i) {              // owner resolves this anchor
            float4 p = pdb[a];
            float apd = (p.z - p.x) * (p.w - p.y);
            float best = -1.f; int bmx = 0;
            #pragma unroll
            for (int mm = 0; mm < M_N; ++mm) {
                float4 gg = s_gt[mm];
                float agt = (gg.z - gg.x) * (gg.w - gg.y);
                float iou = iou_f(gg, p, agt, apd);
                if (iou > best) { best = iou; bmx = mm; }  // first max
            }
            const float sv = score[(base + a) * C_N + s_lb[bmx]];
            const float b2 = best * best;
            const float al = sv * b2 * b2 * b2;  // raw metric (no in_gts)
            s_rm[i] = bmx; s_ral[i] = al;
            atomicMax((int*)&s_pal[bmx], __float_as_int(al));
            atomicMax((int*)&s_pov[bmx], __float_as_int(best));
        }
    }
    __syncthreads();

    // Dense defaults, then scattered overrides.
    for (int i = t; i < A_N; i += 256) d_meta[base + i] = make_uint2(0u, 0u);
    __syncthreads();
    for (int i = t; i < NSLOT; i += 256) {
        const int a = s_sa[i];
        if (a < 0) continue;
        if (s_rm[i] == -2) {                 // single claim
            const int m = i / TOPK;
            int l = s_lb[m]; if (l < 0) l = 0;
            const float nv = s_sm[i] * s_pov[m] / (s_pal[m] + EPSF);
            d_meta[base + a] = make_uint2(0x80000000u | ((unsigned)m << 8) | (unsigned)l,
                                          __float_as_uint(nv));
        } else if (s_rm[i] >= 0) {           // multi owner
            const int m = s_rm[i];
            int l = s_lb[m]; if (l < 0) l = 0;
            const float nv = s_ral[i] * s_pov[m] / (s_pal[m] + EPSF);
            d_meta[base + a] = make_uint2(0x80000000u | ((unsigned)m << 8) | (unsigned)l,
                                          __float_as_uint(nv));
        }
    }
}

// Streaming writer: fillBuffer-shaped, nontemporal stores (proven).
__global__ __launch_bounds__(256) void kC_write(
    const int* __restrict__ labels, const float* __restrict__ gt,
    const uint2* __restrict__ d_meta, float* __restrict__ out)
{
    const int t = threadIdx.x;
    float* out_lbl = out;
    float* out_box = out + (size_t)NBA;
    float* out_sc  = out + (size_t)NBA * 5;
    float* out_fg  = out + (size_t)NBA * (5 + C_N);

    if (blockIdx.x < SCORE_BLKS) {
        const unsigned base = (unsigned)blockIdx.x * 1280u;
        float4* dst = (float4*)out_sc;
        #pragma unroll
        for (int it = 0; it < 5; ++it) {
            const unsigned idx = base + (unsigned)it * 256u + (unsigned)t;
            const unsigned a = idx / 20u;              // global anchor (b*A_N+a)
            const int c4 = (int)(idx - a * 20u) * 4;
            const uint2 mt = d_meta[a];
            const float n = __uint_as_float(mt.y);
            const int L = (mt.x & 0x80000000u) ? (int)(mt.x & 255u) : -1;
            float4 v;
            v.x = (L == c4)     ? n : 0.f;
            v.y = (L == c4 + 1) ? n : 0.f;
            v.z = (L == c4 + 2) ? n : 0.f;
            v.w = (L == c4 + 3) ? n : 0.f;
            nt_store_f4(v, &dst[idx]);
        }
    } else {
        const unsigned rb = (unsigned)blockIdx.x - SCORE_BLKS;
        #pragma unroll
        for (int it = 0; it < 4; ++it) {
            const unsigned a = rb * 1024u + (unsigned)it * 256u + (unsigned)t;
            if (a < (unsigned)NBA) {
                const unsigned b = a / (unsigned)A_N;
                const uint2 mt = d_meta[a];
                const bool fg = (mt.x & 0x80000000u) != 0u;
                const int m = fg ? (int)((mt.x >> 8) & 255u) : 0;
                int l;
                if (fg) l = (int)(mt.x & 255u);
                else { l = labels[b * M_N]; if (l < 0) l = 0; }
                __builtin_nontemporal_store((float)l, &out_lbl[a]);
                const float4 gv = ((const float4*)gt)[b * M_N + m];
                nt_store_f4(gv, &((float4*)out_box)[a]);
                __builtin_nontemporal_store(fg ? 1.f : 0.f, &out_fg[a]);
            }
        }
    }
}

extern "C" void kernel_launch(void* const* d_in, const int* in_sizes, int n_in,
                              void* d_out, int out_size, void* d_ws, size_t ws_size,
                              hipStream_t stream) {
    const float* pd      = (const float*)d_in[0];
    const float* score   = (const float*)d_in[1];
    const int*   labels  = (const int*)d_in[3];
    const float* gt      = (const float*)d_in[4];
    const float* maskgt  = (const float*)d_in[5];
    float* out = (float*)d_out;

    const int NS = BS * NSLOT;               // 13312
    unsigned long long* done = (unsigned long long*)d_ws;   // 256 u64
    uint2* d_meta  = (uint2*)(done + 256);
    int*   cand_idx = (int*)(d_meta + NBA);
    float* cand_met = (float*)(cand_idx + NS);
    float* cand_ov  = cand_met + NS;
    (void)ws_size; (void)in_sizes; (void)n_in;

    kAB<<<256, 256, 0, stream>>>(pd, score, labels, gt, maskgt,
        done, cand_idx, cand_met, cand_ov, d_meta);
    kC_write<<<SCORE_BLKS + REST_BLKS, 256, 0, stream>>>(labels, gt, d_meta, out);
}

// Round 15
// 53.965 us; speedup vs baseline: 1.4497x; 1.4497x over previous
//
#include <hip/hip_runtime.h>

// TaskAlignedAssigner (YOLO TAL) for bs=32, A=8400, M=32, C=80, K=13.
// Outputs (concat, float32): labels [b,A], boxes [b,A,4], scores [b,A,80], fg [b,A].
// 3-kernel design (R13 structure; kA widened to 1024 blocks for 4x TLP):
//   kA_topk   : 1024 blocks (one gt per block, 4 waves) -> 13 slots/gt
//   kB_resolve: 32 blocks (one per batch) -> claim counting + multi-gt
//               resolution + pos maxima -> dense packed d_meta[b,a]
//   kC_write  : fillBuffer-shaped streaming writer (nontemporal stores)

#define BS 32
#define A_N 8400
#define M_N 32
#define C_N 80
#define TOPK 13
#define EPSF 1e-9f
#define NSLOT (M_N * TOPK)     // 416 slots per batch
#define NW ((A_N + 31) / 32)
#define NBA (BS * A_N)         // 268800
#define SCORE_BLKS 4200        // 5,376,000 f4 / 1280 per block
#define REST_BLKS 263          // ceil(268800 / 1024)

typedef float vf4 __attribute__((ext_vector_type(4)));

__device__ __forceinline__ void nt_store_f4(float4 v, float4* p) {
    __builtin_nontemporal_store(*(vf4*)&v, (vf4*)p);
}

__device__ __forceinline__ float iou_f(float4 g, float4 p, float agt, float apd) {
    float lx = fmaxf(g.x, p.x), ly = fmaxf(g.y, p.y);
    float rx = fminf(g.z, p.z), ry = fminf(g.w, p.w);
    float w = fmaxf(rx - lx, 0.f), h = fmaxf(ry - ly, 0.f);
    float inter = w * h;
    return inter / (agt + apd - inter + EPSF);
}

__device__ __forceinline__ unsigned long long umax64(unsigned long long a, unsigned long long b) {
    return a > b ? a : b;
}

// One BLOCK (4 waves) per (b,m): candidates split across 256 threads
// (keys[2] each), per-wave top-13 via shfl-only butterfly passes, then a
// 52-key merge in wave 0 -> global top-13 in s_selk (value desc, index asc
// == jax.lax.top_k tie order). Claims by threads 0..12; zero-fill by wave 0
// (R8-proven owner-lane logic).
__global__ __launch_bounds__(256) void kA_topk(
    const float* __restrict__ pd, const float* __restrict__ score,
    const int* __restrict__ labels, const float* __restrict__ gt,
    const float* __restrict__ maskgt,
    int* __restrict__ cand_idx, float* __restrict__ cand_met,
    float* __restrict__ cand_ov)
{
    __shared__ unsigned long long s_m52[4 * TOPK];   // per-wave top-13
    __shared__ unsigned long long s_selk[TOPK];

    const int t = threadIdx.x;
    const int wave = t >> 6;
    const int lane = t & 63;
    const int bm = blockIdx.x;
    const int b = bm >> 5;

    if (maskgt[bm] <= 0.f) {                 // masked gt -> no candidates
        if (t < TOPK) cand_idx[bm * TOPK + t] = -1;
        return;
    }

    if (t < TOPK) s_selk[t] = 0ull;
    if (t < 4 * TOPK) s_m52[t] = 0ull;

    const float4 g = ((const float4*)gt)[bm];
    const float agt = (g.z - g.x) * (g.w - g.y);
    const float4* pdb = (const float4*)pd + (size_t)b * A_N;
    const int lbl = labels[bm];
    const float* scb = score + (size_t)b * A_N * C_N + lbl;

    // Analytic candidate ranges per stride, fixed up with the EXACT predicate
    // ((i+0.5f)*s vs edge, strict) so membership is bit-exact.
    int il0, nx0, jl0, ny0, il1, nx1, jl1, ny1, il2, nx2, jl2, ny2;
    int c0, c1, c2;
    {
#define RANGE(sv, nv, lo_out, cnt_out, e_lo, e_hi)                         \
        {                                                                  \
            int lo = (int)floorf(e_lo / sv - 0.5f) - 1; lo = max(lo, 0);   \
            while (lo < nv && !(((float)lo + 0.5f) * sv > e_lo)) ++lo;     \
            int hi = (int)ceilf(e_hi / sv - 0.5f) + 1; hi = min(hi, nv-1); \
            while (hi >= 0 && !(((float)hi + 0.5f) * sv < e_hi)) --hi;     \
            lo_out = lo; cnt_out = max(hi - lo + 1, 0);                    \
        }
        RANGE(8.f, 80, il0, nx0, g.x, g.z) RANGE(8.f, 80, jl0, ny0, g.y, g.w)
        RANGE(16.f, 40, il1, nx1, g.x, g.z) RANGE(16.f, 40, jl1, ny1, g.y, g.w)
        RANGE(32.f, 20, il2, nx2, g.x, g.z) RANGE(32.f, 20, jl2, ny2, g.y, g.w)
#undef RANGE
        c0 = nx0 * ny0; c1 = nx1 * ny1; c2 = nx2 * ny2;
    }
    const int T = c0 + c1 + c2;              // <= 305 for wh<=120

    // Each thread owns candidates idx = t and t+256 (T < 512).
    unsigned long long keys[2];
    #pragma unroll
    for (int r = 0; r < 2; ++r) {
        keys[r] = 0ull;
        const int idx = t + r * 256;
        if (idx < T) {
            int q, n, gbase, il, jl, nx;
            if (idx < c0)           { q = idx;           n = 80; gbase = 0;    il = il0; jl = jl0; nx = nx0; }
            else if (idx < c0 + c1) { q = idx - c0;      n = 40; gbase = 6400; il = il1; jl = jl1; nx = nx1; }
            else                    { q = idx - c0 - c1; n = 20; gbase = 8000; il = il2; jl = jl2; nx = nx2; }
            const int row = q / nx, col = q - row * nx;
            const int a = gbase + (jl + row) * n + (il + col);
            float4 p = pdb[a];
            float apd = (p.z - p.x) * (p.w - p.y);
            float iou = iou_f(g, p, agt, apd);
            float sv = scb[(size_t)a * C_N];
            float i2 = iou * iou;
            float met = sv * i2 * i2 * i2;
            if (met > 0.f)
                keys[r] = ((unsigned long long)__float_as_uint(met) << 32)
                        | (unsigned)(~(unsigned)a);
        }
    }

    // Per-wave top-13 (shfl-only; keys unique; 0 = empty).
    unsigned long long pick = 0ull;
    for (int k = 0; k < TOPK; ++k) {
        unsigned long long mx = umax64(keys[0], keys[1]);
        #pragma unroll
        for (int s = 32; s > 0; s >>= 1)
            mx = umax64(mx, (unsigned long long)__shfl_xor((long long)mx, s));
        if (mx == 0ull) break;               // uniform across wave
        if (lane == k) pick = mx;
        if (keys[0] == mx) keys[0] = 0ull;
        if (keys[1] == mx) keys[1] = 0ull;
    }
    if (lane < TOPK) s_m52[wave * TOPK + lane] = pick;
    __syncthreads();

    // Wave 0 merges the 4x13 per-wave winners into the global top-13.
    if (wave == 0) {
        unsigned long long kk = (lane < 4 * TOPK) ? s_m52[lane] : 0ull;
        for (int k = 0; k < TOPK; ++k) {
            unsigned long long mx = kk;
            #pragma unroll
            for (int s = 32; s > 0; s >>= 1)
                mx = umax64(mx, (unsigned long long)__shfl_xor((long long)mx, s));
            if (lane == 0) s_selk[k] = mx;
            if (mx == 0ull) break;
            if (kk == mx) kk = 0ull;
        }
    }
    __syncthreads();

    // Positive-pick claims: thread t owns slot t (single writer).
    if (t < TOPK) {
        const unsigned long long mx = s_selk[t];
        if (mx) {
            const int a = (int)(~(unsigned)(mx & 0xFFFFFFFFu));
            const float v = __uint_as_float((unsigned)(mx >> 32));
            float4 p = pdb[a];
            float apd = (p.z - p.x) * (p.w - p.y);
            const int slot = bm * TOPK + t;
            cand_idx[slot] = a; cand_met[slot] = v; cand_ov[slot] = iou_f(g, p, agt, apd);
        }
    }

    // Zero-fill by wave 0 (all 64 lanes converged; R8-proven logic).
    int npos = 0;
    #pragma unroll
    for (int k = 0; k < TOPK; ++k) npos += (s_selk[k] != 0ull);
    const int nfill = TOPK - npos;
    if (nfill > 0 && wave == 0) {
        // top_k fills remaining slots with metric-0 entries at the LOWEST
        // global anchor indices; nfill>0 => npos<=12 => fill indices < 25.
        bool ing = false; float iou = 0.f, met = 0.f;
        if (lane < 32) {
            const float cx = ((float)lane + 0.5f) * 8.f, cy = 4.0f;
            ing = (cx > g.x) && (cy > g.y) && (cx < g.z) && (cy < g.w);
            if (ing) {
                float4 p = pdb[lane];
                float apd = (p.z - p.x) * (p.w - p.y);
                iou = iou_f(g, p, agt, apd);
                float i2 = iou * iou;
                met = scb[(size_t)lane * C_N] * i2 * i2 * i2;
            }
        }
        const bool z = (lane < 32) && !(met > 0.f);
        const unsigned zm32 = (unsigned)__ballot(z);   // zeros in lanes 0..31
        const int ingi = ing ? 1 : 0;

        // Owner-lane fill: lane L in [npos,TOPK) takes the (L-npos)'th zero.
        // Bit-scan and shuffles run on ALL 64 lanes (converged).
        int q = lane - npos; if (q < 0) q = 0;
        unsigned mm = zm32;
        for (int i = 0; i < q; ++i) mm &= mm - 1;
        const int aq = mm ? __builtin_ctz(mm) : 0;     // zero lane == anchor id
        const int f_ing = __shfl(ingi, aq);
        const float f_iou = __shfl(iou, aq);

        if (lane >= npos && lane < TOPK) {
            const int slot = bm * TOPK + lane;
            if (mm != 0u && f_ing) {         // picked by top_k AND in-gts
                cand_idx[slot] = aq; cand_met[slot] = 0.f; cand_ov[slot] = f_iou;
            } else {
                cand_idx[slot] = -1;
            }
        }
    }
}

// One block per batch (identical to passing R10/R13).
__global__ __launch_bounds__(256) void kB_resolve(
    const float* __restrict__ pd, const float* __restrict__ score,
    const int* __restrict__ labels, const float* __restrict__ gt,
    const int* __restrict__ cand_idx, const float* __restrict__ cand_met,
    const float* __restrict__ cand_ov,
    uint2* __restrict__ d_meta)
{
    __shared__ unsigned s_cnt[A_N];          // 33.6 KB claim counts
    __shared__ int   s_sa[NSLOT];
    __shared__ float s_sm[NSLOT], s_so[NSLOT];
    __shared__ unsigned s_dd[NW];
    __shared__ float s_pal[M_N], s_pov[M_N];
    __shared__ float4 s_gt[M_N];
    __shared__ int s_lb[M_N];
    __shared__ int s_ma[NSLOT], s_mm[NSLOT];
    __shared__ float s_mal[NSLOT];
    __shared__ int s_mc;

    const int b = blockIdx.x;
    const int t = threadIdx.x;
    const size_t base = (size_t)b * A_N;

    for (int i = t; i < A_N; i += 256) s_cnt[i] = 0u;
    for (int i = t; i < NW; i += 256) s_dd[i] = 0u;
    if (t < M_N) {
        s_gt[t] = ((const float4*)gt)[b * M_N + t];
        s_lb[t] = labels[b * M_N + t];
        s_pal[t] = 0.f; s_pov[t] = 0.f;
    }
    if (t == 0) s_mc = 0;
    for (int i = t; i < NSLOT; i += 256) {
        const int gi = b * NSLOT + i;
        s_sa[i] = cand_idx[gi]; s_sm[i] = cand_met[gi]; s_so[i] = cand_ov[gi];
    }
    __syncthreads();

    for (int i = t; i < NSLOT; i += 256) {
        const int a = s_sa[i];
        if (a >= 0) atomicAdd(&s_cnt[a], 1u);
    }
    __syncthreads();

    const float4* pdb = (const float4*)pd + base;
    for (int i = t; i < NSLOT; i += 256) {
        const int a = s_sa[i];
        if (a < 0) continue;
        if (s_cnt[a] == 1u) {
            const int m = i / TOPK;
            atomicMax((int*)&s_pal[m], __float_as_int(s_sm[i]));
            atomicMax((int*)&s_pov[m], __float_as_int(s_so[i]));
        } else {
            const unsigned bit = 1u << (a & 31);
            const unsigned old = atomicOr(&s_dd[a >> 5], bit);
            if (!(old & bit)) {              // one owner resolves this anchor
                float4 p = pdb[a];
                float apd = (p.z - p.x) * (p.w - p.y);
                float best = -1.f; int bmx = 0;
                #pragma unroll
                for (int mm = 0; mm < M_N; ++mm) {
                    float4 gg = s_gt[mm];
                    float agt = (gg.z - gg.x) * (gg.w - gg.y);
                    float iou = iou_f(gg, p, agt, apd);
                    if (iou > best) { best = iou; bmx = mm; }  // first max
                }
                const float sv = score[(base + a) * C_N + s_lb[bmx]];
                const float b2 = best * best;
                const float al = sv * b2 * b2 * b2;  // raw metric (no in_gts)
                const int s = atomicAdd(&s_mc, 1);
                s_ma[s] = a; s_mm[s] = bmx; s_mal[s] = al;
                atomicMax((int*)&s_pal[bmx], __float_as_int(al));
                atomicMax((int*)&s_pov[bmx], __float_as_int(best));
            }
        }
    }
    __syncthreads();

    for (int i = t; i < A_N; i += 256) d_meta[base + i] = make_uint2(0u, 0u);
    __syncthreads();
    for (int i = t; i < NSLOT; i += 256) {
        const int a = s_sa[i];
        if (a < 0 || s_cnt[a] != 1u) continue;
        const int m = i / TOPK;
        int l = s_lb[m]; if (l < 0) l = 0;
        const float nv = s_sm[i] * s_pov[m] / (s_pal[m] + EPSF);
        d_meta[base + a] = make_uint2(0x80000000u | ((unsigned)m << 8) | (unsigned)l,
                                      __float_as_uint(nv));
    }
    const int nm = s_mc;
    for (int i = t; i < nm; i += 256) {
        const int a = s_ma[i], m = s_mm[i];
        int l = s_lb[m]; if (l < 0) l = 0;
        const float nv = s_mal[i] * s_pov[m] / (s_pal[m] + EPSF);
        d_meta[base + a] = make_uint2(0x80000000u | ((unsigned)m << 8) | (unsigned)l,
                                      __float_as_uint(nv));
    }
}

// Streaming writer: fillBuffer-shaped, nontemporal stores (proven R13).
__global__ __launch_bounds__(256) void kC_write(
    const int* __restrict__ labels, const float* __restrict__ gt,
    const uint2* __restrict__ d_meta, float* __restrict__ out)
{
    const int t = threadIdx.x;
    float* out_lbl = out;
    float* out_box = out + (size_t)NBA;
    float* out_sc  = out + (size_t)NBA * 5;
    float* out_fg  = out + (size_t)NBA * (5 + C_N);

    if (blockIdx.x < SCORE_BLKS) {
        const unsigned base = (unsigned)blockIdx.x * 1280u;
        float4* dst = (float4*)out_sc;
        #pragma unroll
        for (int it = 0; it < 5; ++it) {
            const unsigned idx = base + (unsigned)it * 256u + (unsigned)t;
            const unsigned a = idx / 20u;              // global anchor (b*A_N+a)
            const int c4 = (int)(idx - a * 20u) * 4;
            const uint2 mt = d_meta[a];
            const float n = __uint_as_float(mt.y);
            const int L = (mt.x & 0x80000000u) ? (int)(mt.x & 255u) : -1;
            float4 v;
            v.x = (L == c4)     ? n : 0.f;
            v.y = (L == c4 + 1) ? n : 0.f;
            v.z = (L == c4 + 2) ? n : 0.f;
            v.w = (L == c4 + 3) ? n : 0.f;
            nt_store_f4(v, &dst[idx]);
        }
    } else {
        const unsigned rb = (unsigned)blockIdx.x - SCORE_BLKS;
        #pragma unroll
        for (int it = 0; it < 4; ++it) {
            const unsigned a = rb * 1024u + (unsigned)it * 256u + (unsigned)t;
            if (a < (unsigned)NBA) {
                const unsigned b = a / (unsigned)A_N;
                const uint2 mt = d_meta[a];
                const bool fg = (mt.x & 0x80000000u) != 0u;
                const int m = fg ? (int)((mt.x >> 8) & 255u) : 0;
                int l;
                if (fg) l = (int)(mt.x & 255u);
                else { l = labels[b * M_N]; if (l < 0) l = 0; }
                __builtin_nontemporal_store((float)l, &out_lbl[a]);
                const float4 gv = ((const float4*)gt)[b * M_N + m];
                nt_store_f4(gv, &((float4*)out_box)[a]);
                __builtin_nontemporal_store(fg ? 1.f : 0.f, &out_fg[a]);
            }
        }
    }
}

extern "C" void kernel_launch(void* const* d_in, const int* in_sizes, int n_in,
                              void* d_out, int out_size, void* d_ws, size_t ws_size,
                              hipStream_t stream) {
    const float* pd      = (const float*)d_in[0];
    const float* score   = (const float*)d_in[1];
    const int*   labels  = (const int*)d_in[3];
    const float* gt      = (const float*)d_in[4];
    const float* maskgt  = (const float*)d_in[5];
    float* out = (float*)d_out;

    const int NS = BS * NSLOT;               // 13312
    uint2* d_meta  = (uint2*)d_ws;
    int*   cand_idx = (int*)(d_meta + NBA);
    float* cand_met = (float*)(cand_idx + NS);
    float* cand_ov  = cand_met + NS;
    (void)ws_size; (void)in_sizes; (void)n_in;

    kA_topk<<<BS * M_N, 256, 0, stream>>>(pd, score, labels, gt, maskgt,
        cand_idx, cand_met, cand_ov);
    kB_resolve<<<BS, 256, 0, stream>>>(pd, score, labels, gt,
        cand_idx, cand_met, cand_ov, d_meta);
    kC_write<<<SCORE_BLKS + REST_BLKS, 256, 0, stream>>>(labels, gt, d_meta, out);
}

// Round 16
// 49.026 us; speedup vs baseline: 1.5958x; 1.1007x over previous
//
#include <hip/hip_runtime.h>

// TaskAlignedAssigner (YOLO TAL) for bs=32, A=8400, M=32, C=80, K=13.
// Outputs (concat, float32): labels [b,A], boxes [b,A,4], scores [b,A,80], fg [b,A].
// 3-kernel design:
//   kZ_fill : background defaults for ALL outputs (no deps; pure store).
//   kA_topk : 256 blocks, one WAVE per gt -> 13 candidate slots (R13-proven).
//   kB_out  : 32 blocks (one per batch): claim counting + multi-gt resolution
//             + pos maxima, then scatter fg overrides DIRECTLY to out
//             (<=416 anchors/batch; one scalar into the zeroed score row).

#define BS 32
#define A_N 8400
#define M_N 32
#define C_N 80
#define TOPK 13
#define EPSF 1e-9f
#define NSLOT (M_N * TOPK)     // 416 slots per batch
#define NW ((A_N + 31) / 32)
#define NBA (BS * A_N)         // 268800
#define SCORE_BLKS 4200        // 5,376,000 f4 / 1280 per block
#define REST_BLKS 263          // ceil(268800 / 1024)

typedef float vf4 __attribute__((ext_vector_type(4)));

__device__ __forceinline__ void nt_store_f4(float4 v, float4* p) {
    __builtin_nontemporal_store(*(vf4*)&v, (vf4*)p);
}

__device__ __forceinline__ float iou_f(float4 g, float4 p, float agt, float apd) {
    float lx = fmaxf(g.x, p.x), ly = fmaxf(g.y, p.y);
    float rx = fminf(g.z, p.z), ry = fminf(g.w, p.w);
    float w = fmaxf(rx - lx, 0.f), h = fmaxf(ry - ly, 0.f);
    float inter = w * h;
    return inter / (agt + apd - inter + EPSF);
}

__device__ __forceinline__ unsigned long long umax64(unsigned long long a, unsigned long long b) {
    return a > b ? a : b;
}

// Background writer: scores all-zero (no loads — pure fill), labels/box/fg
// from batch-constant bg values. fg anchors are overwritten later by kB_out.
__global__ __launch_bounds__(256) void kZ_fill(
    const int* __restrict__ labels, const float* __restrict__ gt,
    float* __restrict__ out)
{
    const int t = threadIdx.x;
    float* out_lbl = out;
    float* out_box = out + (size_t)NBA;
    float* out_sc  = out + (size_t)NBA * 5;
    float* out_fg  = out + (size_t)NBA * (5 + C_N);

    if (blockIdx.x < SCORE_BLKS) {
        const unsigned base = (unsigned)blockIdx.x * 1280u;
        float4* dst = (float4*)out_sc;
        const float4 z = make_float4(0.f, 0.f, 0.f, 0.f);
        #pragma unroll
        for (int it = 0; it < 5; ++it)
            nt_store_f4(z, &dst[base + (unsigned)it * 256u + (unsigned)t]);
    } else {
        const unsigned rb = (unsigned)blockIdx.x - SCORE_BLKS;
        #pragma unroll
        for (int it = 0; it < 4; ++it) {
            const unsigned a = rb * 1024u + (unsigned)it * 256u + (unsigned)t;
            if (a < (unsigned)NBA) {
                const unsigned b = a / (unsigned)A_N;
                int l = labels[b * M_N]; if (l < 0) l = 0;
                __builtin_nontemporal_store((float)l, &out_lbl[a]);
                const float4 gv = ((const float4*)gt)[b * M_N];
                nt_store_f4(gv, &((float4*)out_box)[a]);
                __builtin_nontemporal_store(0.f, &out_fg[a]);
            }
        }
    }
}

// One WAVE per (b,m). Identical to the passing R8/R9/R10/R13 kernel.
__global__ __launch_bounds__(256) void kA_topk(
    const float* __restrict__ pd, const float* __restrict__ score,
    const int* __restrict__ labels, const float* __restrict__ gt,
    const float* __restrict__ maskgt,
    int* __restrict__ cand_idx, float* __restrict__ cand_met,
    float* __restrict__ cand_ov)
{
    const int wave = threadIdx.x >> 6;
    const int lane = threadIdx.x & 63;
    const int bm = blockIdx.x * 4 + wave;
    const int b = bm >> 5;

    if (maskgt[bm] <= 0.f) {                 // masked gt -> no candidates
        if (lane < TOPK) cand_idx[bm * TOPK + lane] = -1;
        return;
    }

    const float4 g = ((const float4*)gt)[bm];
    const float agt = (g.z - g.x) * (g.w - g.y);
    const float4* pdb = (const float4*)pd + (size_t)b * A_N;
    const int lbl = labels[bm];
    const float* scb = score + (size_t)b * A_N * C_N + lbl;

    int il0, nx0, jl0, ny0, il1, nx1, jl1, ny1, il2, nx2, jl2, ny2;
    int c0, c1, c2;
    {
#define RANGE(sv, nv, lo_out, cnt_out, e_lo, e_hi)                         \
        {                                                                  \
            int lo = (int)floorf(e_lo / sv - 0.5f) - 1; lo = max(lo, 0);   \
            while (lo < nv && !(((float)lo + 0.5f) * sv > e_lo)) ++lo;     \
            int hi = (int)ceilf(e_hi / sv - 0.5f) + 1; hi = min(hi, nv-1); \
            while (hi >= 0 && !(((float)hi + 0.5f) * sv < e_hi)) --hi;     \
            lo_out = lo; cnt_out = max(hi - lo + 1, 0);                    \
        }
        RANGE(8.f, 80, il0, nx0, g.x, g.z) RANGE(8.f, 80, jl0, ny0, g.y, g.w)
        RANGE(16.f, 40, il1, nx1, g.x, g.z) RANGE(16.f, 40, jl1, ny1, g.y, g.w)
        RANGE(32.f, 20, il2, nx2, g.x, g.z) RANGE(32.f, 20, jl2, ny2, g.y, g.w)
#undef RANGE
        c0 = nx0 * ny0; c1 = nx1 * ny1; c2 = nx2 * ny2;
    }
    const int T = c0 + c1 + c2;              // <= 305 for wh<=120

    unsigned long long keys[6];
    #pragma unroll
    for (int r = 0; r < 6; ++r) {
        keys[r] = 0ull;
        const int idx = r * 64 + lane;
        if (idx < T) {
            int q, n, gbase, il, jl, nx;
            if (idx < c0)           { q = idx;           n = 80; gbase = 0;    il = il0; jl = jl0; nx = nx0; }
            else if (idx < c0 + c1) { q = idx - c0;      n = 40; gbase = 6400; il = il1; jl = jl1; nx = nx1; }
            else                    { q = idx - c0 - c1; n = 20; gbase = 8000; il = il2; jl = jl2; nx = nx2; }
            const int row = q / nx, col = q - row * nx;
            const int a = gbase + (jl + row) * n + (il + col);
            float4 p = pdb[a];
            float apd = (p.z - p.x) * (p.w - p.y);
            float iou = iou_f(g, p, agt, apd);
            float sv = scb[(size_t)a * C_N];
            float i2 = iou * iou;
            float met = sv * i2 * i2 * i2;
            if (met > 0.f)
                keys[r] = ((unsigned long long)__float_as_uint(met) << 32)
                        | (unsigned)(~(unsigned)a);
        }
    }

    unsigned long long pick = 0ull;
    for (int k = 0; k < TOPK; ++k) {
        unsigned long long mx = 0ull;
        #pragma unroll
        for (int r = 0; r < 6; ++r) mx = umax64(mx, keys[r]);
        #pragma unroll
        for (int s = 32; s > 0; s >>= 1)
            mx = umax64(mx, (unsigned long long)__shfl_xor((long long)mx, s));
        if (mx == 0ull) break;               // uniform across wave
        if (lane == k) pick = mx;
        #pragma unroll
        for (int r = 0; r < 6; ++r) if (keys[r] == mx) keys[r] = 0ull;
    }

    if (lane < TOPK && pick) {
        const int a = (int)(~(unsigned)(pick & 0xFFFFFFFFu));
        const float v = __uint_as_float((unsigned)(pick >> 32));
        float4 p = pdb[a];
        float apd = (p.z - p.x) * (p.w - p.y);
        const int slot = bm * TOPK + lane;
        cand_idx[slot] = a; cand_met[slot] = v; cand_ov[slot] = iou_f(g, p, agt, apd);
    }

    const int npos = __popcll(__ballot(pick != 0ull));
    const int nfill = TOPK - npos;
    if (nfill > 0) {
        bool ing = false; float iou = 0.f, met = 0.f;
        if (lane < 32) {
            const float cx = ((float)lane + 0.5f) * 8.f, cy = 4.0f;
            ing = (cx > g.x) && (cy > g.y) && (cx < g.z) && (cy < g.w);
            if (ing) {
                float4 p = pdb[lane];
                float apd = (p.z - p.x) * (p.w - p.y);
                iou = iou_f(g, p, agt, apd);
                float i2 = iou * iou;
                met = scb[(size_t)lane * C_N] * i2 * i2 * i2;
            }
        }
        const bool z = (lane < 32) && !(met > 0.f);
        const unsigned zm32 = (unsigned)__ballot(z);
        const int ingi = ing ? 1 : 0;

        int q = lane - npos; if (q < 0) q = 0;
        unsigned mm = zm32;
        for (int i = 0; i < q; ++i) mm &= mm - 1;
        const int aq = mm ? __builtin_ctz(mm) : 0;
        const int f_ing = __shfl(ingi, aq);
        const float f_iou = __shfl(iou, aq);

        if (lane >= npos && lane < TOPK) {
            const int slot = bm * TOPK + lane;
            if (mm != 0u && f_ing) {
                cand_idx[slot] = aq; cand_met[slot] = 0.f; cand_ov[slot] = f_iou;
            } else {
                cand_idx[slot] = -1;
            }
        }
    }
}

// One block per batch: resolution (identical arithmetic to R10/R13) +
// direct scatter of fg overrides into the pre-filled output.
__global__ __launch_bounds__(256) void kB_out(
    const float* __restrict__ pd, const float* __restrict__ score,
    const int* __restrict__ labels, const float* __restrict__ gt,
    const int* __restrict__ cand_idx, const float* __restrict__ cand_met,
    const float* __restrict__ cand_ov,
    float* __restrict__ out)
{
    __shared__ unsigned s_cnt[A_N];          // 33.6 KB claim counts
    __shared__ int   s_sa[NSLOT];
    __shared__ float s_sm[NSLOT], s_so[NSLOT];
    __shared__ unsigned s_dd[NW];
    __shared__ float s_pal[M_N], s_pov[M_N];
    __shared__ float4 s_gt[M_N];
    __shared__ int s_lb[M_N];
    __shared__ int s_ma[NSLOT], s_mm[NSLOT];
    __shared__ float s_mal[NSLOT];
    __shared__ int s_mc;

    const int b = blockIdx.x;
    const int t = threadIdx.x;
    const size_t base = (size_t)b * A_N;

    float* out_lbl = out;
    float* out_box = out + (size_t)NBA;
    float* out_sc  = out + (size_t)NBA * 5;
    float* out_fg  = out + (size_t)NBA * (5 + C_N);

    for (int i = t; i < A_N; i += 256) s_cnt[i] = 0u;
    for (int i = t; i < NW; i += 256) s_dd[i] = 0u;
    if (t < M_N) {
        s_gt[t] = ((const float4*)gt)[b * M_N + t];
        s_lb[t] = labels[b * M_N + t];
        s_pal[t] = 0.f; s_pov[t] = 0.f;
    }
    if (t == 0) s_mc = 0;
    for (int i = t; i < NSLOT; i += 256) {
        const int gi = b * NSLOT + i;
        s_sa[i] = cand_idx[gi]; s_sm[i] = cand_met[gi]; s_so[i] = cand_ov[gi];
    }
    __syncthreads();

    for (int i = t; i < NSLOT; i += 256) {
        const int a = s_sa[i];
        if (a >= 0) atomicAdd(&s_cnt[a], 1u);
    }
    __syncthreads();

    const float4* pdb = (const float4*)pd + base;
    for (int i = t; i < NSLOT; i += 256) {
        const int a = s_sa[i];
        if (a < 0) continue;
        if (s_cnt[a] == 1u) {
            const int m = i / TOPK;
            atomicMax((int*)&s_pal[m], __float_as_int(s_sm[i]));
            atomicMax((int*)&s_pov[m], __float_as_int(s_so[i]));
        } else {
            const unsigned bit = 1u << (a & 31);
            const unsigned old = atomicOr(&s_dd[a >> 5], bit);
            if (!(old & bit)) {              // one owner resolves this anchor
                float4 p = pdb[a];
                float apd = (p.z - p.x) * (p.w - p.y);
                float best = -1.f; int bmx = 0;
                #pragma unroll
                for (int mm = 0; mm < M_N; ++mm) {
                    float4 gg = s_gt[mm];
                    float agt = (gg.z - gg.x) * (gg.w - gg.y);
                    float iou = iou_f(gg, p, agt, apd);
                    if (iou > best) { best = iou; bmx = mm; }  // first max
                }
                const float sv = score[(base + a) * C_N + s_lb[bmx]];
                const float b2 = best * best;
                const float al = sv * b2 * b2 * b2;  // raw metric (no in_gts)
                const int s = atomicAdd(&s_mc, 1);
                s_ma[s] = a; s_mm[s] = bmx; s_mal[s] = al;
                atomicMax((int*)&s_pal[bmx], __float_as_int(al));
                atomicMax((int*)&s_pov[bmx], __float_as_int(best));
            }
        }
    }
    __syncthreads();

    // Scatter fg overrides (singles: unique anchors; multis: owner only).
    for (int i = t; i < NSLOT; i += 256) {
        const int a = s_sa[i];
        if (a < 0 || s_cnt[a] != 1u) continue;
        const int m = i / TOPK;
        int l = s_lb[m]; if (l < 0) l = 0;
        const float nv = s_sm[i] * s_pov[m] / (s_pal[m] + EPSF);
        out_lbl[base + a] = (float)l;
        ((float4*)out_box)[base + a] = s_gt[m];
        out_fg[base + a] = 1.f;
        out_sc[(base + a) * C_N + l] = nv;   // row already zeroed by kZ
    }
    const int nm = s_mc;
    for (int i = t; i < nm; i += 256) {
        const int a = s_ma[i], m = s_mm[i];
        int l = s_lb[m]; if (l < 0) l = 0;
        const float nv = s_mal[i] * s_pov[m] / (s_pal[m] + EPSF);
        out_lbl[base + a] = (float)l;
        ((float4*)out_box)[base + a] = s_gt[m];
        out_fg[base + a] = 1.f;
        out_sc[(base + a) * C_N + l] = nv;
    }
}

extern "C" void kernel_launch(void* const* d_in, const int* in_sizes, int n_in,
                              void* d_out, int out_size, void* d_ws, size_t ws_size,
                              hipStream_t stream) {
    const float* pd      = (const float*)d_in[0];
    const float* score   = (const float*)d_in[1];
    const int*   labels  = (const int*)d_in[3];
    const float* gt      = (const float*)d_in[4];
    const float* maskgt  = (const float*)d_in[5];
    float* out = (float*)d_out;

    const int NS = BS * NSLOT;               // 13312
    int*   cand_idx = (int*)d_ws;
    float* cand_met = (float*)(cand_idx + NS);
    float* cand_ov  = cand_met + NS;
    (void)ws_size; (void)in_sizes; (void)n_in;

    kZ_fill<<<SCORE_BLKS + REST_BLKS, 256, 0, stream>>>(labels, gt, out);
    kA_topk<<<BS * M_N / 4, 256, 0, stream>>>(pd, score, labels, gt, maskgt,
        cand_idx, cand_met, cand_ov);
    kB_out<<<BS, 256, 0, stream>>>(pd, score, labels, gt,
        cand_idx, cand_met, cand_ov, out);
}

// Round 17
// 40.227 us; speedup vs baseline: 1.9449x; 1.2187x over previous
//
#include <hip/hip_runtime.h>

// TaskAlignedAssigner (YOLO TAL) for bs=32, A=8400, M=32, C=80, K=13.
// Outputs (concat, float32): labels [b,A], boxes [b,A,4], scores [b,A,80], fg [b,A].
// 2-kernel design:
//   kZA   : merged independent work — blocks 0..255 run the proven kA_topk
//           (one WAVE per gt -> 13 slots); remaining 4463 blocks write the
//           background defaults (score zeros + bg lbl/box/fg). Store-bound
//           fill overlaps latency-bound gather.
//   kB_out: 32 blocks (one per batch): claim counting + multi-gt resolution
//           + pos maxima, then scatter fg overrides directly to out.

#define BS 32
#define A_N 8400
#define M_N 32
#define C_N 80
#define TOPK 13
#define EPSF 1e-9f
#define NSLOT (M_N * TOPK)     // 416 slots per batch
#define NW ((A_N + 31) / 32)
#define NBA (BS * A_N)         // 268800
#define TOPK_BLKS 256
#define SCORE_BLKS 4200        // 5,376,000 f4 / 1280 per block
#define REST_BLKS 263          // ceil(268800 / 1024)

typedef float vf4 __attribute__((ext_vector_type(4)));

__device__ __forceinline__ void nt_store_f4(float4 v, float4* p) {
    __builtin_nontemporal_store(*(vf4*)&v, (vf4*)p);
}

__device__ __forceinline__ float iou_f(float4 g, float4 p, float agt, float apd) {
    float lx = fmaxf(g.x, p.x), ly = fmaxf(g.y, p.y);
    float rx = fminf(g.z, p.z), ry = fminf(g.w, p.w);
    float w = fmaxf(rx - lx, 0.f), h = fmaxf(ry - ly, 0.f);
    float inter = w * h;
    return inter / (agt + apd - inter + EPSF);
}

__device__ __forceinline__ unsigned long long umax64(unsigned long long a, unsigned long long b) {
    return a > b ? a : b;
}

__global__ __launch_bounds__(256) void kZA(
    const float* __restrict__ pd, const float* __restrict__ score,
    const int* __restrict__ labels, const float* __restrict__ gt,
    const float* __restrict__ maskgt,
    int* __restrict__ cand_idx, float* __restrict__ cand_met,
    float* __restrict__ cand_ov, float* __restrict__ out)
{
    const int t = threadIdx.x;

    if (blockIdx.x >= TOPK_BLKS) {
        // ---------------- background fill (R16 kZ body) ----------------
        float* out_lbl = out;
        float* out_box = out + (size_t)NBA;
        float* out_sc  = out + (size_t)NBA * 5;
        float* out_fg  = out + (size_t)NBA * (5 + C_N);
        const unsigned fb = (unsigned)blockIdx.x - TOPK_BLKS;

        if (fb < SCORE_BLKS) {
            const unsigned base = fb * 1280u;
            float4* dst = (float4*)out_sc;
            const float4 z = make_float4(0.f, 0.f, 0.f, 0.f);
            #pragma unroll
            for (int it = 0; it < 5; ++it)
                nt_store_f4(z, &dst[base + (unsigned)it * 256u + (unsigned)t]);
        } else {
            const unsigned rb = fb - SCORE_BLKS;
            #pragma unroll
            for (int it = 0; it < 4; ++it) {
                const unsigned a = rb * 1024u + (unsigned)it * 256u + (unsigned)t;
                if (a < (unsigned)NBA) {
                    const unsigned b = a / (unsigned)A_N;
                    int l = labels[b * M_N]; if (l < 0) l = 0;
                    __builtin_nontemporal_store((float)l, &out_lbl[a]);
                    const float4 gv = ((const float4*)gt)[b * M_N];
                    nt_store_f4(gv, &((float4*)out_box)[a]);
                    __builtin_nontemporal_store(0.f, &out_fg[a]);
                }
            }
        }
        return;
    }

    // ---------------- topk: proven kA_topk body ----------------
    const int wave = t >> 6;
    const int lane = t & 63;
    const int bm = blockIdx.x * 4 + wave;
    const int b = bm >> 5;

    if (maskgt[bm] <= 0.f) {                 // masked gt -> no candidates
        if (lane < TOPK) cand_idx[bm * TOPK + lane] = -1;
        return;
    }

    const float4 g = ((const float4*)gt)[bm];
    const float agt = (g.z - g.x) * (g.w - g.y);
    const float4* pdb = (const float4*)pd + (size_t)b * A_N;
    const int lbl = labels[bm];
    const float* scb = score + (size_t)b * A_N * C_N + lbl;

    int il0, nx0, jl0, ny0, il1, nx1, jl1, ny1, il2, nx2, jl2, ny2;
    int c0, c1, c2;
    {
#define RANGE(sv, nv, lo_out, cnt_out, e_lo, e_hi)                         \
        {                                                                  \
            int lo = (int)floorf(e_lo / sv - 0.5f) - 1; lo = max(lo, 0);   \
            while (lo < nv && !(((float)lo + 0.5f) * sv > e_lo)) ++lo;     \
            int hi = (int)ceilf(e_hi / sv - 0.5f) + 1; hi = min(hi, nv-1); \
            while (hi >= 0 && !(((float)hi + 0.5f) * sv < e_hi)) --hi;     \
            lo_out = lo; cnt_out = max(hi - lo + 1, 0);                    \
        }
        RANGE(8.f, 80, il0, nx0, g.x, g.z) RANGE(8.f, 80, jl0, ny0, g.y, g.w)
        RANGE(16.f, 40, il1, nx1, g.x, g.z) RANGE(16.f, 40, jl1, ny1, g.y, g.w)
        RANGE(32.f, 20, il2, nx2, g.x, g.z) RANGE(32.f, 20, jl2, ny2, g.y, g.w)
#undef RANGE
        c0 = nx0 * ny0; c1 = nx1 * ny1; c2 = nx2 * ny2;
    }
    const int T = c0 + c1 + c2;              // <= 305 for wh<=120

    unsigned long long keys[6];
    #pragma unroll
    for (int r = 0; r < 6; ++r) {
        keys[r] = 0ull;
        const int idx = r * 64 + lane;
        if (idx < T) {
            int q, n, gbase, il, jl, nx;
            if (idx < c0)           { q = idx;           n = 80; gbase = 0;    il = il0; jl = jl0; nx = nx0; }
            else if (idx < c0 + c1) { q = idx - c0;      n = 40; gbase = 6400; il = il1; jl = jl1; nx = nx1; }
            else                    { q = idx - c0 - c1; n = 20; gbase = 8000; il = il2; jl = jl2; nx = nx2; }
            const int row = q / nx, col = q - row * nx;
            const int a = gbase + (jl + row) * n + (il + col);
            float4 p = pdb[a];
            float apd = (p.z - p.x) * (p.w - p.y);
            float iou = iou_f(g, p, agt, apd);
            float sv = scb[(size_t)a * C_N];
            float i2 = iou * iou;
            float met = sv * i2 * i2 * i2;
            if (met > 0.f)
                keys[r] = ((unsigned long long)__float_as_uint(met) << 32)
                        | (unsigned)(~(unsigned)a);
        }
    }

    unsigned long long pick = 0ull;
    for (int k = 0; k < TOPK; ++k) {
        unsigned long long mx = 0ull;
        #pragma unroll
        for (int r = 0; r < 6; ++r) mx = umax64(mx, keys[r]);
        #pragma unroll
        for (int s = 32; s > 0; s >>= 1)
            mx = umax64(mx, (unsigned long long)__shfl_xor((long long)mx, s));
        if (mx == 0ull) break;               // uniform across wave
        if (lane == k) pick = mx;
        #pragma unroll
        for (int r = 0; r < 6; ++r) if (keys[r] == mx) keys[r] = 0ull;
    }

    if (lane < TOPK && pick) {
        const int a = (int)(~(unsigned)(pick & 0xFFFFFFFFu));
        const float v = __uint_as_float((unsigned)(pick >> 32));
        float4 p = pdb[a];
        float apd = (p.z - p.x) * (p.w - p.y);
        const int slot = bm * TOPK + lane;
        cand_idx[slot] = a; cand_met[slot] = v; cand_ov[slot] = iou_f(g, p, agt, apd);
    }

    const int npos = __popcll(__ballot(pick != 0ull));
    const int nfill = TOPK - npos;
    if (nfill > 0) {
        bool ing = false; float iou = 0.f, met = 0.f;
        if (lane < 32) {
            const float cx = ((float)lane + 0.5f) * 8.f, cy = 4.0f;
            ing = (cx > g.x) && (cy > g.y) && (cx < g.z) && (cy < g.w);
            if (ing) {
                float4 p = pdb[lane];
                float apd = (p.z - p.x) * (p.w - p.y);
                iou = iou_f(g, p, agt, apd);
                float i2 = iou * iou;
                met = scb[(size_t)lane * C_N] * i2 * i2 * i2;
            }
        }
        const bool z = (lane < 32) && !(met > 0.f);
        const unsigned zm32 = (unsigned)__ballot(z);
        const int ingi = ing ? 1 : 0;

        int q = lane - npos; if (q < 0) q = 0;
        unsigned mm = zm32;
        for (int i = 0; i < q; ++i) mm &= mm - 1;
        const int aq = mm ? __builtin_ctz(mm) : 0;
        const int f_ing = __shfl(ingi, aq);
        const float f_iou = __shfl(iou, aq);

        if (lane >= npos && lane < TOPK) {
            const int slot = bm * TOPK + lane;
            if (mm != 0u && f_ing) {
                cand_idx[slot] = aq; cand_met[slot] = 0.f; cand_ov[slot] = f_iou;
            } else {
                cand_idx[slot] = -1;
            }
        }
    }
}

// One block per batch: resolution + direct fg scatter (identical to R16).
__global__ __launch_bounds__(256) void kB_out(
    const float* __restrict__ pd, const float* __restrict__ score,
    const int* __restrict__ labels, const float* __restrict__ gt,
    const int* __restrict__ cand_idx, const float* __restrict__ cand_met,
    const float* __restrict__ cand_ov,
    float* __restrict__ out)
{
    __shared__ unsigned s_cnt[A_N];          // 33.6 KB claim counts
    __shared__ int   s_sa[NSLOT];
    __shared__ float s_sm[NSLOT], s_so[NSLOT];
    __shared__ unsigned s_dd[NW];
    __shared__ float s_pal[M_N], s_pov[M_N];
    __shared__ float4 s_gt[M_N];
    __shared__ int s_lb[M_N];
    __shared__ int s_ma[NSLOT], s_mm[NSLOT];
    __shared__ float s_mal[NSLOT];
    __shared__ int s_mc;

    const int b = blockIdx.x;
    const int t = threadIdx.x;
    const size_t base = (size_t)b * A_N;

    float* out_lbl = out;
    float* out_box = out + (size_t)NBA;
    float* out_sc  = out + (size_t)NBA * 5;
    float* out_fg  = out + (size_t)NBA * (5 + C_N);

    for (int i = t; i < A_N; i += 256) s_cnt[i] = 0u;
    for (int i = t; i < NW; i += 256) s_dd[i] = 0u;
    if (t < M_N) {
        s_gt[t] = ((const float4*)gt)[b * M_N + t];
        s_lb[t] = labels[b * M_N + t];
        s_pal[t] = 0.f; s_pov[t] = 0.f;
    }
    if (t == 0) s_mc = 0;
    for (int i = t; i < NSLOT; i += 256) {
        const int gi = b * NSLOT + i;
        s_sa[i] = cand_idx[gi]; s_sm[i] = cand_met[gi]; s_so[i] = cand_ov[gi];
    }
    __syncthreads();

    for (int i = t; i < NSLOT; i += 256) {
        const int a = s_sa[i];
        if (a >= 0) atomicAdd(&s_cnt[a], 1u);
    }
    __syncthreads();

    const float4* pdb = (const float4*)pd + base;
    for (int i = t; i < NSLOT; i += 256) {
        const int a = s_sa[i];
        if (a < 0) continue;
        if (s_cnt[a] == 1u) {
            const int m = i / TOPK;
            atomicMax((int*)&s_pal[m], __float_as_int(s_sm[i]));
            atomicMax((int*)&s_pov[m], __float_as_int(s_so[i]));
        } else {
            const unsigned bit = 1u << (a & 31);
            const unsigned old = atomicOr(&s_dd[a >> 5], bit);
            if (!(old & bit)) {              // one owner resolves this anchor
                float4 p = pdb[a];
                float apd = (p.z - p.x) * (p.w - p.y);
                float best = -1.f; int bmx = 0;
                #pragma unroll
                for (int mm = 0; mm < M_N; ++mm) {
                    float4 gg = s_gt[mm];
                    float agt = (gg.z - gg.x) * (gg.w - gg.y);
                    float iou = iou_f(gg, p, agt, apd);
                    if (iou > best) { best = iou; bmx = mm; }  // first max
                }
                const float sv = score[(base + a) * C_N + s_lb[bmx]];
                const float b2 = best * best;
                const float al = sv * b2 * b2 * b2;  // raw metric (no in_gts)
                const int s = atomicAdd(&s_mc, 1);
                s_ma[s] = a; s_mm[s] = bmx; s_mal[s] = al;
                atomicMax((int*)&s_pal[bmx], __float_as_int(al));
                atomicMax((int*)&s_pov[bmx], __float_as_int(best));
            }
        }
    }
    __syncthreads();

    // Scatter fg overrides (singles: unique anchors; multis: owner only).
    for (int i = t; i < NSLOT; i += 256) {
        const int a = s_sa[i];
        if (a < 0 || s_cnt[a] != 1u) continue;
        const int m = i / TOPK;
        int l = s_lb[m]; if (l < 0) l = 0;
        const float nv = s_sm[i] * s_pov[m] / (s_pal[m] + EPSF);
        out_lbl[base + a] = (float)l;
        ((float4*)out_box)[base + a] = s_gt[m];
        out_fg[base + a] = 1.f;
        out_sc[(base + a) * C_N + l] = nv;   // row already zeroed by fill
    }
    const int nm = s_mc;
    for (int i = t; i < nm; i += 256) {
        const int a = s_ma[i], m = s_mm[i];
        int l = s_lb[m]; if (l < 0) l = 0;
        const float nv = s_mal[i] * s_pov[m] / (s_pal[m] + EPSF);
        out_lbl[base + a] = (float)l;
        ((float4*)out_box)[base + a] = s_gt[m];
        out_fg[base + a] = 1.f;
        out_sc[(base + a) * C_N + l] = nv;
    }
}

extern "C" void kernel_launch(void* const* d_in, const int* in_sizes, int n_in,
                              void* d_out, int out_size, void* d_ws, size_t ws_size,
                              hipStream_t stream) {
    const float* pd      = (const float*)d_in[0];
    const float* score   = (const float*)d_in[1];
    const int*   labels  = (const int*)d_in[3];
    const float* gt      = (const float*)d_in[4];
    const float* maskgt  = (const float*)d_in[5];
    float* out = (float*)d_out;

    const int NS = BS * NSLOT;               // 13312
    int*   cand_idx = (int*)d_ws;
    float* cand_met = (float*)(cand_idx + NS);
    float* cand_ov  = cand_met + NS;
    (void)ws_size; (void)in_sizes; (void)n_in;

    kZA<<<TOPK_BLKS + SCORE_BLKS + REST_BLKS, 256, 0, stream>>>(
        pd, score, labels, gt, maskgt, cand_idx, cand_met, cand_ov, out);
    kB_out<<<BS, 256, 0, stream>>>(pd, score, labels, gt,
        cand_idx, cand_met, cand_ov, out);
}